// Round 14
// baseline (503.481 us; speedup 1.0000x reference)
//
#include <hip/hip_runtime.h>
#include <math.h>

#define MIN_NORM 1e-15f
#define BALL_EPS 4e-3f
#define BSH 7                 // bucket shift: 128 rows per bucket
#define BW  128
#define NBMAX 512

typedef __attribute__((ext_vector_type(8))) short bf16x8;
typedef __attribute__((ext_vector_type(4))) float f32x4;

__device__ __forceinline__ short f2bf(float f) {
  unsigned u = __builtin_bit_cast(unsigned, f);
  u = u + 0x7FFFu + ((u >> 16) & 1u);   // RNE
  return (short)(u >> 16);
}
__device__ __forceinline__ float bf2f(unsigned short us) {
  unsigned u = ((unsigned)us) << 16;
  return __builtin_bit_cast(float, u);
}

__device__ __forceinline__ float wsum(float v) {
#pragma unroll
  for (int off = 32; off; off >>= 1) v += __shfl_xor(v, off, 64);
  return v;
}

__device__ __forceinline__ float artanh_clip(float z) {
  z = fminf(fmaxf(z, -1.0f + 1e-7f), 1.0f - 1e-7f);
  return 0.5f * (log1pf(z) - log1pf(-z));
}

// Kprep: blocks 0..15 convert W -> bf16 fragment layout; block 16 zeroes bucket_total.
// w_frag[((kk*4+t)*4+g)*16+m][j] = bf16(W[(kk*32+g*8+j)*64 + t*16+m])
__global__ __launch_bounds__(256) void kprep(
    const float* __restrict__ W, unsigned short* __restrict__ w_frag,
    int* __restrict__ bucket_total) {
  if (blockIdx.x == 16) {
    for (int i = threadIdx.x; i < NBMAX; i += 256) bucket_total[i] = 0;
    return;
  }
  int base = blockIdx.x * 256 + threadIdx.x;
#pragma unroll
  for (int r = 0; r < 4; ++r) {
    int o = base + r * 4096;
    int j = o & 7, m = (o >> 3) & 15, g = (o >> 7) & 3, t = (o >> 9) & 3, kk = o >> 11;
    w_frag[o] = (unsigned short)f2bf(W[(kk * 32 + g * 8 + j) * 64 + t * 16 + m]);
  }
}

// K1: blocks [0,G1) MFMA GEMM (mx = x@W, x2 = ||x||^2); blocks [G1,..) bucket count.
__global__ __launch_bounds__(256) void k1_gemm_count(
    const float* __restrict__ x, const unsigned short* __restrict__ w_frag,
    float* __restrict__ mx_ws, float* __restrict__ x2_ws, int N,
    const int* __restrict__ row, int* __restrict__ bucket_total, int E,
    int G1, int ECHUNK) {
  if ((int)blockIdx.x >= G1) {
    __shared__ int lhist[NBMAX];
    int cb = blockIdx.x - G1;
    for (int i = threadIdx.x; i < NBMAX; i += 256) lhist[i] = 0;
    __syncthreads();
    int st = cb * ECHUNK;
    int en = min(E, st + ECHUNK);
    for (int i = st + (int)threadIdx.x; i < en; i += 256)
      atomicAdd(&lhist[row[i] >> BSH], 1);
    __syncthreads();
    for (int i = threadIdx.x; i < NBMAX; i += 256)
      if (lhist[i]) atomicAdd(&bucket_total[i], lhist[i]);
    return;
  }
  const int lane = threadIdx.x & 63;
  const int wid = threadIdx.x >> 6;
  const int m = lane & 15;
  const int g = lane >> 4;

  // coalesced fragment loads: 16B per lane per (kk,t)
  bf16x8 b[8][4];
#pragma unroll
  for (int kk = 0; kk < 8; ++kk)
#pragma unroll
    for (int t = 0; t < 4; ++t)
      b[kk][t] = *(const bf16x8*)&w_frag[(size_t)((kk * 4 + t) * 64 + lane) * 8];

  const int nb16 = (N + 15) >> 4;
  const int wstep = G1 * 4;
  for (int rb = blockIdx.x * 4 + wid; rb < nb16; rb += wstep) {
    int arow = rb * 16 + m;
    if (arow >= N) arow = N - 1;
    const float* xp = &x[(size_t)arow * 256 + g * 8];

    bf16x8 a[8];
    float x2p = 0.f;
#pragma unroll
    for (int kk = 0; kk < 8; ++kk) {
      float4 v0 = *(const float4*)(xp + kk * 32);
      float4 v1 = *(const float4*)(xp + kk * 32 + 4);
      x2p += v0.x * v0.x + v0.y * v0.y + v0.z * v0.z + v0.w * v0.w +
             v1.x * v1.x + v1.y * v1.y + v1.z * v1.z + v1.w * v1.w;
      bf16x8 aa;
      aa[0] = f2bf(v0.x); aa[1] = f2bf(v0.y); aa[2] = f2bf(v0.z); aa[3] = f2bf(v0.w);
      aa[4] = f2bf(v1.x); aa[5] = f2bf(v1.y); aa[6] = f2bf(v1.z); aa[7] = f2bf(v1.w);
      a[kk] = aa;
    }
    float x2f = x2p;
    x2f += __shfl_xor(x2f, 16, 64);
    x2f += __shfl_xor(x2f, 32, 64);

    f32x4 acc[4];
#pragma unroll
    for (int t = 0; t < 4; ++t) { acc[t][0] = 0.f; acc[t][1] = 0.f; acc[t][2] = 0.f; acc[t][3] = 0.f; }
#pragma unroll
    for (int kk = 0; kk < 8; ++kk)
#pragma unroll
      for (int t = 0; t < 4; ++t)
        acc[t] = __builtin_amdgcn_mfma_f32_16x16x32_bf16(a[kk], b[kk][t], acc[t], 0, 0, 0);

#pragma unroll
    for (int j = 0; j < 4; ++j) {
      int orow = rb * 16 + g * 4 + j;
      if (orow < N) {
        float* mp = &mx_ws[(size_t)orow * 64 + m];
#pragma unroll
        for (int t = 0; t < 4; ++t) mp[t * 16] = acc[t][j];
      }
    }
    if (g == 0 && rb * 16 + m < N) x2_ws[rb * 16 + m] = x2f;
  }
}

// K2: blocks [0,k1bBlocks) hyperbolic per-row math; block k1bBlocks = bucket scan.
__global__ __launch_bounds__(256) void k2_hyp_scan(
    const float* __restrict__ mx_ws, const float* __restrict__ x2_ws,
    const float* __restrict__ bias, const float* __restrict__ cptr,
    unsigned short* __restrict__ h, int N, int k1bBlocks,
    const int* __restrict__ bucket_total, int* __restrict__ gbase,
    int* __restrict__ gcursor, int NB) {
  if ((int)blockIdx.x >= k1bBlocks) {
    if (threadIdx.x < 64) {
      int tid = threadIdx.x;
      int running = 0;
      for (int kk = 0; kk < 8; ++kk) {
        int idx = kk * 64 + tid;
        int v = (idx < NB) ? bucket_total[idx] : 0;
        int s = v;
#pragma unroll
        for (int d = 1; d < 64; d <<= 1) { int t = __shfl_up(s, d, 64); if (tid >= d) s += t; }
        if (idx < NB) { int ex = running + s - v; gbase[idx] = ex; gcursor[idx] = ex; }
        running += __shfl(s, 63, 64);
      }
      if (tid == 0) gbase[NB] = running;
    }
    return;
  }
  const int lane = threadIdx.x & 63;
  const int wid = threadIdx.x >> 6;
  const int sub = lane >> 4;
  const int q = lane & 15;
  const float c = *cptr;
  const float sc = sqrtf(c);
  const float maxnorm = (1.0f - BALL_EPS) / sc;

  float4 bv = *(const float4*)&bias[q * 4];
  float bsq = bv.x * bv.x + bv.y * bv.y + bv.z * bv.z + bv.w * bv.w;
#pragma unroll
  for (int o = 1; o < 16; o <<= 1) bsq += __shfl_xor(bsq, o, 64);
  float bnorm = fmaxf(sqrtf(bsq), MIN_NORM);
  float tb = tanhf(sc * bnorm);
  float bfac = tb / (sc * bnorm);
  float hbn = fmaxf(tb / sc, MIN_NORM);
  float pfac = (hbn > maxnorm) ? (maxnorm / hbn) : 1.0f;
  float hb0 = bv.x * bfac * pfac, hb1 = bv.y * bfac * pfac;
  float hb2 = bv.z * bfac * pfac, hb3 = bv.w * bfac * pfac;
  float y2 = hb0 * hb0 + hb1 * hb1 + hb2 * hb2 + hb3 * hb3;
#pragma unroll
  for (int o = 1; o < 16; o <<= 1) y2 += __shfl_xor(y2, o, 64);

  const int r = (blockIdx.x * 4 + wid) * 4 + sub;
  if (r >= N) return;

  float4 mv = *(const float4*)&mx_ws[(size_t)r * 64 + q * 4];
  float x2v = x2_ws[r];

  float msq = mv.x * mv.x + mv.y * mv.y + mv.z * mv.z + mv.w * mv.w;
  int z = (mv.x == 0.f) && (mv.y == 0.f) && (mv.z == 0.f) && (mv.w == 0.f);
#pragma unroll
  for (int o = 1; o < 16; o <<= 1) {
    msq += __shfl_xor(msq, o, 64);
    z &= __shfl_xor(z, o, 64);
  }
  float mx_norm = fmaxf(sqrtf(msq), MIN_NORM);
  float x_norm = fmaxf(sqrtf(x2v), MIN_NORM);
  float art = artanh_clip(sc * x_norm);
  float tt = tanhf(mx_norm / x_norm * art);
  float fac = z ? 0.f : (tt / (mx_norm * sc));
  float r0 = mv.x * fac, r1 = mv.y * fac, r2 = mv.z * fac, r3 = mv.w * fac;

  float x2m = r0 * r0 + r1 * r1 + r2 * r2 + r3 * r3;
  float xy = r0 * hb0 + r1 * hb1 + r2 * hb2 + r3 * hb3;
#pragma unroll
  for (int o = 1; o < 16; o <<= 1) {
    x2m += __shfl_xor(x2m, o, 64);
    xy += __shfl_xor(xy, o, 64);
  }
  float k2 = 1.f + 2.f * c * xy;
  float ca = k2 + c * y2;
  float cb = 1.f - c * x2m;
  float inv = 1.f / fmaxf(k2 + c * c * x2m * y2, MIN_NORM);
  float a0 = (ca * r0 + cb * hb0) * inv;
  float a1 = (ca * r1 + cb * hb1) * inv;
  float a2 = (ca * r2 + cb * hb2) * inv;
  float a3 = (ca * r3 + cb * hb3) * inv;

  float psq = a0 * a0 + a1 * a1 + a2 * a2 + a3 * a3;
#pragma unroll
  for (int o = 1; o < 16; o <<= 1) psq += __shfl_xor(psq, o, 64);
  float p_norm = fmaxf(sqrtf(psq), MIN_NORM);
  float art2 = artanh_clip(sc * p_norm);
  float fac2 = art2 / (sc * p_norm);

  ushort4 hv;
  hv.x = (unsigned short)f2bf(a0 * fac2);
  hv.y = (unsigned short)f2bf(a1 * fac2);
  hv.z = (unsigned short)f2bf(a2 * fac2);
  hv.w = (unsigned short)f2bf(a3 * fac2);
  *(ushort4*)&h[(size_t)r * 64 + q * 4] = hv;
}

// K3: LDS-staged binned scatter. Records 8B: meta = (rowl<<16)|col, val.
__global__ __launch_bounds__(256) void k3_binscatter(
    const int* __restrict__ row, const int* __restrict__ col,
    const float* __restrict__ vals, int* __restrict__ gcursor,
    uint2* __restrict__ bins, int E, int NB) {
  __shared__ uint2 stag[4096];
  __shared__ int dstoff[4096];
  __shared__ int hist[NBMAX], lbase[NBMAX], off[NBMAX];
  const int tid = threadIdx.x;
  const int st = blockIdx.x * 4096;
  const int n = min(4096, E - st);
  for (int i = tid; i < NBMAX; i += 256) hist[i] = 0;
  __syncthreads();
  for (int i = tid; i < n; i += 256) atomicAdd(&hist[row[st + i] >> BSH], 1);
  __syncthreads();
  if (tid < 64) {
    int running = 0;
    for (int k = 0; k < 8; ++k) {
      int idx = k * 64 + tid;
      int v = hist[idx];
      int s = v;
#pragma unroll
      for (int d = 1; d < 64; d <<= 1) { int t = __shfl_up(s, d, 64); if (tid >= d) s += t; }
      lbase[idx] = running + s - v;
      running += __shfl(s, 63, 64);
    }
  }
  __syncthreads();
  for (int b = tid; b < NB; b += 256) {
    int cnt = hist[b];
    int go = cnt ? atomicAdd(&gcursor[b], cnt) : 0;
    off[b] = go - lbase[b];
  }
  __syncthreads();
  for (int i = tid; i < NBMAX; i += 256) hist[i] = 0;
  __syncthreads();
  for (int i = tid; i < n; i += 256) {
    int r = row[st + i];
    int b = r >> BSH;
    unsigned meta = ((unsigned)(r & (BW - 1)) << 16) | (unsigned)col[st + i];
    int rank = atomicAdd(&hist[b], 1);
    int slot = lbase[b] + rank;
    stag[slot] = make_uint2(meta, __builtin_bit_cast(unsigned, vals[st + i]));
    dstoff[slot] = off[b];
  }
  __syncthreads();
  for (int i = tid; i < n; i += 256) bins[dstoff[i] + i] = stag[i];
}

// K4: one wg per bucket; LDS fp32 accumulator; fused expmap0+proj epilogue.
__global__ __launch_bounds__(256) void k4_binsum(
    const unsigned short* __restrict__ h, const uint2* __restrict__ bins,
    const int* __restrict__ gbase, const float* __restrict__ cptr,
    float* __restrict__ out, int N) {
  __shared__ float acc[BW * 64];   // 32 KB
  const int tid = threadIdx.x;
  const int lane = tid & 63;
  const int wid = tid >> 6;
  const int g = wid * 4 + (lane >> 4);   // group 0..15
  const int q = lane & 15;
  const int k = q >> 3;                  // edge slot 0..1
  const int qq = q & 7;                  // dim octet
  const int b = blockIdx.x;
  for (int i = tid * 4; i < BW * 64; i += 1024)
    *(float4*)&acc[i] = make_float4(0.f, 0.f, 0.f, 0.f);
  __syncthreads();
  int st = gbase[b], en = gbase[b + 1];
  st = __builtin_amdgcn_readfirstlane(st);
  en = __builtin_amdgcn_readfirstlane(en);

#define PROC(EE)                                                            \
  {                                                                         \
    uint2 rec = bins[EE];                                                   \
    unsigned cc = rec.x & 0xFFFFu;                                          \
    unsigned rowl = rec.x >> 16;                                            \
    float v = __builtin_bit_cast(float, rec.y);                             \
    bf16x8 hv = *(const bf16x8*)&h[(size_t)cc * 64 + qq * 8];               \
    float* ap = &acc[rowl * 64 + qq * 8];                                   \
    _Pragma("unroll")                                                       \
    for (int j = 0; j < 8; ++j)                                             \
      atomicAdd(ap + j, v * bf2f((unsigned short)hv[j]));                   \
  }

  int e = st + g * 2 + k;
  for (; e + 32 < en; e += 64) { PROC(e); PROC(e + 32); }
  if (e < en) PROC(e);
#undef PROC
  __syncthreads();

  const float c = *cptr;
  const float sc = sqrtf(c);
  const float maxnorm = (1.0f - BALL_EPS) / sc;
#pragma unroll
  for (int it = 0; it < BW / 16; ++it) {
    int rl = it * 16 + g;
    int grow = b * BW + rl;
    float4 a = *(float4*)&acc[rl * 64 + q * 4];
    float sq = a.x * a.x + a.y * a.y + a.z * a.z + a.w * a.w;
#pragma unroll
    for (int o = 1; o < 16; o <<= 1) sq += __shfl_xor(sq, o, 64);
    float un = fmaxf(sqrtf(sq), MIN_NORM);
    float th = tanhf(sc * un);
    float fac = th / (sc * un);
    float p0 = a.x * fac, p1 = a.y * fac, p2 = a.z * fac, p3 = a.w * fac;
    float psq = p0 * p0 + p1 * p1 + p2 * p2 + p3 * p3;
#pragma unroll
    for (int o = 1; o < 16; o <<= 1) psq += __shfl_xor(psq, o, 64);
    float pn = fmaxf(sqrtf(psq), MIN_NORM);
    if (pn > maxnorm) { float pf = maxnorm / pn; p0 *= pf; p1 *= pf; p2 *= pf; p3 *= pf; }
    if (grow < N)
      *(float4*)&out[(size_t)grow * 64 + q * 4] = make_float4(p0, p1, p2, p3);
  }
}

// ---- fallback (atomic path, bf16 h) ----
__global__ __launch_bounds__(256) void edge_kernel(
    const unsigned short* __restrict__ h, const float* __restrict__ vals,
    const int* __restrict__ row, const int* __restrict__ col,
    float* __restrict__ out, int E) {
  const int lane = threadIdx.x & 63;
  const int wid0 = (blockIdx.x * blockDim.x + threadIdx.x) >> 6;
  const int nw = (gridDim.x * blockDim.x) >> 6;
  for (int e = wid0; e < E; e += nw) {
    int eu = __builtin_amdgcn_readfirstlane(e);
    float v = vals[eu];
    int r = row[eu];
    int cl = col[eu];
    atomicAdd(&out[(size_t)r * 64 + lane], v * bf2f(h[(size_t)cl * 64 + lane]));
  }
}

__global__ __launch_bounds__(256) void final_kernel(
    float* __restrict__ out, const float* __restrict__ cptr, int N) {
  const int lane = threadIdx.x & 63;
  const int wid0 = (blockIdx.x * blockDim.x + threadIdx.x) >> 6;
  const int nw = (gridDim.x * blockDim.x) >> 6;
  const float c = *cptr;
  const float sc = sqrtf(c);
  const float maxnorm = (1.0f - BALL_EPS) / sc;
  for (int r = wid0; r < N; r += nw) {
    float u = out[(size_t)r * 64 + lane];
    float un = fmaxf(sqrtf(wsum(u * u)), MIN_NORM);
    float th = tanhf(sc * un);
    float p = th * u / (sc * un);
    float pn = fmaxf(sqrtf(wsum(p * p)), MIN_NORM);
    if (pn > maxnorm) p = p / pn * maxnorm;
    out[(size_t)r * 64 + lane] = p;
  }
}

static inline size_t align256(size_t x) { return (x + 255) & ~(size_t)255; }

extern "C" void kernel_launch(void* const* d_in, const int* in_sizes, int n_in,
                              void* d_out, int out_size, void* d_ws, size_t ws_size,
                              hipStream_t stream) {
  const float* x = (const float*)d_in[0];      // [N,256]
  const float* W = (const float*)d_in[1];      // [256,64]
  const float* bias = (const float*)d_in[2];   // [64]
  const float* vals = (const float*)d_in[3];   // [E]
  const float* cptr = (const float*)d_in[4];   // scalar
  const int* row = (const int*)d_in[5];        // [E]
  const int* col = (const int*)d_in[6];        // [E]
  float* out = (float*)d_out;                  // [N,64]

  const int OUT = in_sizes[2];                 // 64
  const int IN = in_sizes[1] / OUT;            // 256
  const int N = in_sizes[0] / IN;              // 50000
  const int E = in_sizes[3];                   // 800000

  // ws: w_frag | mx (aliased by bins) | x2 | h | bucket_total | gbase | gcursor
  char* ws = (char*)d_ws;
  size_t o_wf = 0;
  size_t o_mx = align256(o_wf + 16384 * 2);
  size_t o_x2 = align256(o_mx + (size_t)N * 64 * 4);
  size_t o_h = align256(o_x2 + (size_t)N * 4);
  size_t o_bt = align256(o_h + (size_t)N * 64 * 2);
  size_t o_gb = align256(o_bt + NBMAX * 4);
  size_t o_gc = align256(o_gb + (NBMAX + 1) * 4);
  size_t needed = o_gc + NBMAX * 4;

  unsigned short* w_frag = (unsigned short*)(ws + o_wf);
  float* mx_ws = (float*)(ws + o_mx);
  float* x2_ws = (float*)(ws + o_x2);
  unsigned short* h = (unsigned short*)(ws + o_h);
  int* bucket_total = (int*)(ws + o_bt);
  int* gbase = (int*)(ws + o_gb);
  int* gcursor = (int*)(ws + o_gc);
  uint2* bins = (uint2*)(ws + o_mx);           // alias: mx dead after K2

  const int NB = (N + BW - 1) / BW;
  const int nb16 = (N + 15) / 16;
  const int G1 = 782;
  const int CB = 100;
  const int ECHUNK = (E + CB - 1) / CB;
  const int k1bBlocks = (N + 15) / 16;

  bool fast = (needed <= ws_size) && (N <= 65536) && (NB <= NBMAX) &&
              ((size_t)E * 8 <= (size_t)N * 256) && (E > 0);

  if (fast) {
    kprep<<<17, 256, 0, stream>>>(W, w_frag, bucket_total);
    k1_gemm_count<<<G1 + CB, 256, 0, stream>>>(x, w_frag, mx_ws, x2_ws, N,
                                               row, bucket_total, E, G1, ECHUNK);
    k2_hyp_scan<<<k1bBlocks + 1, 256, 0, stream>>>(mx_ws, x2_ws, bias, cptr, h, N,
                                                   k1bBlocks, bucket_total, gbase,
                                                   gcursor, NB);
    k3_binscatter<<<(E + 4095) / 4096, 256, 0, stream>>>(row, col, vals, gcursor,
                                                         bins, E, NB);
    k4_binsum<<<NB, 256, 0, stream>>>(h, bins, gbase, cptr, out, N);
  } else {
    kprep<<<17, 256, 0, stream>>>(W, w_frag, bucket_total);
    k1_gemm_count<<<G1, 256, 0, stream>>>(x, w_frag, mx_ws, x2_ws, N,
                                          row, (int*)nullptr, 0, G1, ECHUNK);
    k2_hyp_scan<<<k1bBlocks, 256, 0, stream>>>(mx_ws, x2_ws, bias, cptr, h, N,
                                               k1bBlocks + 1, bucket_total, gbase,
                                               gcursor, NB);
    hipMemsetAsync(d_out, 0, (size_t)out_size * sizeof(float), stream);
    edge_kernel<<<2048, 256, 0, stream>>>(h, vals, row, col, out, E);
    final_kernel<<<1024, 256, 0, stream>>>(out, cptr, N);
  }
}